// Round 1
// baseline (398.720 us; speedup 1.0000x reference)
//
#include <hip/hip_runtime.h>
#include <hip/hip_bf16.h>

#define N_FEAT 128   // D_FEAT == UNITS == 128

// ---------------------------------------------------------------------------
// K1: degree histograms (int atomics)
// ---------------------------------------------------------------------------
__global__ void hist_kernel(const int* __restrict__ source,
                            const int* __restrict__ target,
                            int* __restrict__ deg_out,
                            int* __restrict__ deg_in, int E) {
    int e = blockIdx.x * blockDim.x + threadIdx.x;
    if (e >= E) return;
    atomicAdd(&deg_out[source[e]], 1);
    atomicAdd(&deg_in[target[e]], 1);
}

// ---------------------------------------------------------------------------
// K2: scales = rsqrt(max(deg,1))
// ---------------------------------------------------------------------------
__global__ void scale_kernel(const int* __restrict__ deg_out,
                             const int* __restrict__ deg_in,
                             float* __restrict__ so, float* __restrict__ ri,
                             int N) {
    int i = blockIdx.x * blockDim.x + threadIdx.x;
    if (i >= N) return;
    int d_o = deg_out[i]; if (d_o < 1) d_o = 1;
    int d_i = deg_in[i];  if (d_i < 1) d_i = 1;
    so[i] = rsqrtf((float)d_o);
    ri[i] = rsqrtf((float)d_i);
}

// ---------------------------------------------------------------------------
// K3: exclusive prefix sum of deg_in -> offsets (single block, 1024 threads)
// ---------------------------------------------------------------------------
__global__ void scan_kernel(const int* __restrict__ deg_in,
                            int* __restrict__ offsets, int N) {
    __shared__ int buf[1024];
    __shared__ int base_s;
    int tid = threadIdx.x;
    if (tid == 0) base_s = 0;
    __syncthreads();
    for (int chunk = 0; chunk < N; chunk += 1024) {
        int i = chunk + tid;
        int v = (i < N) ? deg_in[i] : 0;
        buf[tid] = v;
        __syncthreads();
        // Hillis-Steele inclusive scan
        for (int off = 1; off < 1024; off <<= 1) {
            int t = (tid >= off) ? buf[tid - off] : 0;
            __syncthreads();
            buf[tid] += t;
            __syncthreads();
        }
        int incl = buf[tid];
        int base = base_s;
        if (i < N) offsets[i] = base + incl - v;
        __syncthreads();                      // all read base_s before update
        if (tid == 1023) base_s = base + incl; // buf[1023] = chunk total
        __syncthreads();
    }
    if (tid == 0) offsets[N] = base_s;
}

// ---------------------------------------------------------------------------
// K4: fill CSR edge lists (sources bucketed by target)
// ---------------------------------------------------------------------------
__global__ void fill_kernel(const int* __restrict__ source,
                            const int* __restrict__ target,
                            const int* __restrict__ offsets,
                            int* __restrict__ cursor,
                            int* __restrict__ elist, int E) {
    int e = blockIdx.x * blockDim.x + threadIdx.x;
    if (e >= E) return;
    int t = target[e];
    int p = atomicAdd(&cursor[t], 1);
    elist[offsets[t] + p] = source[e];
}

// ---------------------------------------------------------------------------
// K5: pull aggregation — one wave per target node, float2 per lane.
// pooled row = ri[t] * sum_{s in in(t)} so[s] * x[s]
// Writes into `pooled` (= d_out, overwritten by GEMM in-place later).
// ---------------------------------------------------------------------------
__global__ void agg_kernel(const float* __restrict__ x,
                           const int* __restrict__ elist,
                           const int* __restrict__ offsets,
                           const float* __restrict__ so,
                           const float* __restrict__ ri,
                           float* __restrict__ pooled, int N) {
    int wave = (blockIdx.x * blockDim.x + threadIdx.x) >> 6;
    int lane = threadIdx.x & 63;
    if (wave >= N) return;
    int start = offsets[wave];
    int end   = offsets[wave + 1];
    float2 acc = make_float2(0.f, 0.f);
    for (int i = start; i < end; ++i) {
        int s = __builtin_amdgcn_readfirstlane(elist[i]); // uniform -> scalar addr
        float sc = so[s];
        float2 v = *(const float2*)(&x[s * N_FEAT + lane * 2]);
        acc.x += sc * v.x;
        acc.y += sc * v.y;
    }
    float r = ri[wave];
    *(float2*)(&pooled[(size_t)wave * N_FEAT + lane * 2]) =
        make_float2(acc.x * r, acc.y * r);
}

// ---------------------------------------------------------------------------
// K6: out = relu(P @ W + b), fp32, in-place on P (each block reads only the
// 64 rows it writes, staged to LDS before any store).
// Tile: 64 rows x 128 cols per 256-thread block; thread computes 4x8.
// ---------------------------------------------------------------------------
#define PSTR 132   // padded row stride for P tile (bank-spread, 16B aligned)
#define KCHUNK 32

__global__ __launch_bounds__(256) void gemm_kernel(const float* __restrict__ W,
                                                   const float* __restrict__ bias,
                                                   float* __restrict__ P, // in/out
                                                   int N) {
    __shared__ float Pl[64 * PSTR];      // 33792 B
    __shared__ float Wl[KCHUNK * 128];   // 16384 B  (total 50176 B < 64 KB)
    int tid = threadIdx.x;
    int rbase = blockIdx.x * 64;

    // stage P tile (zero-fill OOB rows)
    #pragma unroll
    for (int i = 0; i < 8; ++i) {
        int idx = tid + i * 256;       // float4 index 0..2047
        int flat = idx * 4;            // 0..8191
        int r = flat >> 7, c = flat & 127;
        int gr = rbase + r;
        float4 p4 = (gr < N) ? *(const float4*)(&P[(size_t)gr * N_FEAT + c])
                             : make_float4(0.f, 0.f, 0.f, 0.f);
        *(float4*)(&Pl[r * PSTR + c]) = p4;
    }

    int r0 = (tid >> 4) * 4;
    int c0 = (tid & 15) * 8;
    float acc[4][8] = {};

    for (int kc = 0; kc < 128; kc += KCHUNK) {
        __syncthreads();
        // stage W chunk: KCHUNK x 128
        #pragma unroll
        for (int i = 0; i < (KCHUNK * 128 / 4) / 256; ++i) {
            int idx = tid + i * 256;   // float4 index
            int flat = idx * 4;
            int kk = flat >> 7, c = flat & 127;
            *(float4*)(&Wl[kk * 128 + c]) =
                *(const float4*)(&W[(kc + kk) * N_FEAT + c]);
        }
        __syncthreads();
        #pragma unroll
        for (int k2 = 0; k2 < KCHUNK; k2 += 4) {
            float4 pr[4];
            #pragma unroll
            for (int i = 0; i < 4; ++i)
                pr[i] = *(const float4*)(&Pl[(r0 + i) * PSTR + kc + k2]);
            #pragma unroll
            for (int j = 0; j < 4; ++j) {
                float4 wa = *(const float4*)(&Wl[(k2 + j) * 128 + c0]);
                float4 wb = *(const float4*)(&Wl[(k2 + j) * 128 + c0 + 4]);
                #pragma unroll
                for (int i = 0; i < 4; ++i) {
                    float pv = ((const float*)&pr[i])[j];
                    acc[i][0] += pv * wa.x; acc[i][1] += pv * wa.y;
                    acc[i][2] += pv * wa.z; acc[i][3] += pv * wa.w;
                    acc[i][4] += pv * wb.x; acc[i][5] += pv * wb.y;
                    acc[i][6] += pv * wb.z; acc[i][7] += pv * wb.w;
                }
            }
        }
    }

    float4 b0 = *(const float4*)(&bias[c0]);
    float4 b1 = *(const float4*)(&bias[c0 + 4]);
    #pragma unroll
    for (int i = 0; i < 4; ++i) {
        int gr = rbase + r0 + i;
        if (gr < N) {
            float4 o0, o1;
            o0.x = fmaxf(acc[i][0] + b0.x, 0.f);
            o0.y = fmaxf(acc[i][1] + b0.y, 0.f);
            o0.z = fmaxf(acc[i][2] + b0.z, 0.f);
            o0.w = fmaxf(acc[i][3] + b0.w, 0.f);
            o1.x = fmaxf(acc[i][4] + b1.x, 0.f);
            o1.y = fmaxf(acc[i][5] + b1.y, 0.f);
            o1.z = fmaxf(acc[i][6] + b1.z, 0.f);
            o1.w = fmaxf(acc[i][7] + b1.w, 0.f);
            *(float4*)(&P[(size_t)gr * N_FEAT + c0])     = o0;
            *(float4*)(&P[(size_t)gr * N_FEAT + c0 + 4]) = o1;
        }
    }
}

// ---------------------------------------------------------------------------
extern "C" void kernel_launch(void* const* d_in, const int* in_sizes, int n_in,
                              void* d_out, int out_size, void* d_ws, size_t ws_size,
                              hipStream_t stream) {
    const float* x      = (const float*)d_in[0];
    const int*   source = (const int*)d_in[1];
    const int*   target = (const int*)d_in[2];
    const float* W      = (const float*)d_in[3];
    const float* bias   = (const float*)d_in[4];
    float*       out    = (float*)d_out;

    const int N = in_sizes[0] / N_FEAT;   // 50000
    const int E = in_sizes[1];            // 800000

    // workspace carve (aligned to 256 B)
    uintptr_t p = (uintptr_t)d_ws;
    auto carve = [&](size_t bytes) {
        p = (p + 255) & ~(uintptr_t)255;
        uintptr_t r = p;
        p += bytes;
        return (void*)r;
    };
    int*   counts  = (int*)carve((size_t)3 * N * sizeof(int)); // deg_out|deg_in|cursor
    int*   deg_out = counts;
    int*   deg_in  = counts + N;
    int*   cursor  = counts + 2 * N;
    float* so      = (float*)carve((size_t)N * sizeof(float));
    float* ri      = (float*)carve((size_t)N * sizeof(float));
    int*   offsets = (int*)carve((size_t)(N + 1) * sizeof(int));
    int*   elist   = (int*)carve((size_t)E * sizeof(int));
    (void)ws_size; (void)n_in; (void)out_size;

    hipMemsetAsync(counts, 0, (size_t)3 * N * sizeof(int), stream);

    hist_kernel<<<(E + 255) / 256, 256, 0, stream>>>(source, target, deg_out, deg_in, E);
    scale_kernel<<<(N + 255) / 256, 256, 0, stream>>>(deg_out, deg_in, so, ri, N);
    scan_kernel<<<1, 1024, 0, stream>>>(deg_in, offsets, N);
    fill_kernel<<<(E + 255) / 256, 256, 0, stream>>>(source, target, offsets, cursor, elist, E);
    agg_kernel<<<(N + 3) / 4, 256, 0, stream>>>(x, elist, offsets, so, ri, out, N);
    gemm_kernel<<<(N + 63) / 64, 256, 0, stream>>>(W, bias, out, N);
}

// Round 2
// 290.925 us; speedup vs baseline: 1.3705x; 1.3705x over previous
//
#include <hip/hip_runtime.h>
#include <hip/hip_bf16.h>

#define N_FEAT 128   // D_FEAT == UNITS == 128

// ---------------------------------------------------------------------------
// K1: degree histograms (int atomics)
// ---------------------------------------------------------------------------
__global__ void hist_kernel(const int* __restrict__ source,
                            const int* __restrict__ target,
                            int* __restrict__ deg_out,
                            int* __restrict__ deg_in, int E) {
    int e = blockIdx.x * blockDim.x + threadIdx.x;
    if (e >= E) return;
    atomicAdd(&deg_out[source[e]], 1);
    atomicAdd(&deg_in[target[e]], 1);
}

// ---------------------------------------------------------------------------
// K2: scales = rsqrt(max(deg,1))
// ---------------------------------------------------------------------------
__global__ void scale_kernel(const int* __restrict__ deg_out,
                             const int* __restrict__ deg_in,
                             float* __restrict__ so, float* __restrict__ ri,
                             int N) {
    int i = blockIdx.x * blockDim.x + threadIdx.x;
    if (i >= N) return;
    int d_o = deg_out[i]; if (d_o < 1) d_o = 1;
    int d_i = deg_in[i];  if (d_i < 1) d_i = 1;
    so[i] = rsqrtf((float)d_o);
    ri[i] = rsqrtf((float)d_i);
}

// ---------------------------------------------------------------------------
// K3a/b/c: hierarchical exclusive scan of deg_in -> offsets
// (replaces the 90 us single-block scan: one CU was doing all 50k elements)
// ---------------------------------------------------------------------------
__global__ void block_reduce_kernel(const int* __restrict__ deg,
                                    int* __restrict__ bsum, int N) {
    __shared__ int sb[256];
    int tid = threadIdx.x;
    int i = blockIdx.x * 256 + tid;
    sb[tid] = (i < N) ? deg[i] : 0;
    __syncthreads();
    #pragma unroll
    for (int off = 128; off > 0; off >>= 1) {
        if (tid < off) sb[tid] += sb[tid + off];
        __syncthreads();
    }
    if (tid == 0) bsum[blockIdx.x] = sb[0];
}

// single block, nb <= 256: exclusive scan of block sums in place
__global__ void scan_bsum_kernel(int* __restrict__ bsum, int nb) {
    __shared__ int sb[256];
    int tid = threadIdx.x;
    int v = (tid < nb) ? bsum[tid] : 0;
    sb[tid] = v;
    __syncthreads();
    #pragma unroll
    for (int off = 1; off < 256; off <<= 1) {
        int t = (tid >= off) ? sb[tid - off] : 0;
        __syncthreads();
        sb[tid] += t;
        __syncthreads();
    }
    if (tid < nb) bsum[tid] = sb[tid] - v;   // exclusive
}

__global__ void scan_final_kernel(const int* __restrict__ deg,
                                  const int* __restrict__ bsum,
                                  int* __restrict__ offsets, int N, int E) {
    __shared__ int sb[256];
    int tid = threadIdx.x;
    int i = blockIdx.x * 256 + tid;
    int v = (i < N) ? deg[i] : 0;
    sb[tid] = v;
    __syncthreads();
    #pragma unroll
    for (int off = 1; off < 256; off <<= 1) {
        int t = (tid >= off) ? sb[tid - off] : 0;
        __syncthreads();
        sb[tid] += t;
        __syncthreads();
    }
    if (i < N) offsets[i] = bsum[blockIdx.x] + sb[tid] - v;
    if (blockIdx.x == 0 && tid == 0) offsets[N] = E;  // total is always E
}

// ---------------------------------------------------------------------------
// K4: fill CSR edge lists (sources bucketed by target)
// ---------------------------------------------------------------------------
__global__ void fill_kernel(const int* __restrict__ source,
                            const int* __restrict__ target,
                            const int* __restrict__ offsets,
                            int* __restrict__ cursor,
                            int* __restrict__ elist, int E) {
    int e = blockIdx.x * blockDim.x + threadIdx.x;
    if (e >= E) return;
    int t = target[e];
    int p = atomicAdd(&cursor[t], 1);
    elist[offsets[t] + p] = source[e];
}

// ---------------------------------------------------------------------------
// K5: pull aggregation — one wave per target node, float2 per lane.
// Unrolled x4: 4 independent x-row loads in flight per iteration (was 1 ->
// latency-bound at VALUBusy 12.7%). 4 separate accumulators break the FMA
// dependence chain too.
// ---------------------------------------------------------------------------
__global__ void agg_kernel(const float* __restrict__ x,
                           const int* __restrict__ elist,
                           const int* __restrict__ offsets,
                           const float* __restrict__ so,
                           const float* __restrict__ ri,
                           float* __restrict__ pooled, int N) {
    int wave = (blockIdx.x * blockDim.x + threadIdx.x) >> 6;
    int lane = threadIdx.x & 63;
    if (wave >= N) return;
    int start = offsets[wave];
    int end   = offsets[wave + 1];
    int col = lane * 2;

    float2 a0 = make_float2(0.f, 0.f), a1 = a0, a2 = a0, a3 = a0;
    int i = start;
    for (; i + 4 <= end; i += 4) {
        int e0 = __builtin_amdgcn_readfirstlane(elist[i]);
        int e1 = __builtin_amdgcn_readfirstlane(elist[i + 1]);
        int e2 = __builtin_amdgcn_readfirstlane(elist[i + 2]);
        int e3 = __builtin_amdgcn_readfirstlane(elist[i + 3]);
        float s0 = so[e0], s1 = so[e1], s2 = so[e2], s3 = so[e3];
        float2 v0 = *(const float2*)(&x[(size_t)e0 * N_FEAT + col]);
        float2 v1 = *(const float2*)(&x[(size_t)e1 * N_FEAT + col]);
        float2 v2 = *(const float2*)(&x[(size_t)e2 * N_FEAT + col]);
        float2 v3 = *(const float2*)(&x[(size_t)e3 * N_FEAT + col]);
        a0.x += s0 * v0.x; a0.y += s0 * v0.y;
        a1.x += s1 * v1.x; a1.y += s1 * v1.y;
        a2.x += s2 * v2.x; a2.y += s2 * v2.y;
        a3.x += s3 * v3.x; a3.y += s3 * v3.y;
    }
    for (; i < end; ++i) {
        int e = __builtin_amdgcn_readfirstlane(elist[i]);
        float s = so[e];
        float2 v = *(const float2*)(&x[(size_t)e * N_FEAT + col]);
        a0.x += s * v.x; a0.y += s * v.y;
    }
    float r = ri[wave];
    float2 outv = make_float2((a0.x + a1.x + a2.x + a3.x) * r,
                              (a0.y + a1.y + a2.y + a3.y) * r);
    *(float2*)(&pooled[(size_t)wave * N_FEAT + col]) = outv;
}

// ---------------------------------------------------------------------------
// K6: out = relu(P @ W + b), fp32, in-place on P (each block reads only the
// 64 rows it writes, staged to LDS before any store).
// Tile: 64 rows x 128 cols per 256-thread block; thread computes 4x8.
// fp32 GEMM kept deliberately: bf16-MFMA rounding tail (~2e-2) is too close
// to the 2.56e-2 absmax threshold.
// ---------------------------------------------------------------------------
#define PSTR 132   // padded row stride for P tile (bank-spread, 16B aligned)
#define KCHUNK 32

__global__ __launch_bounds__(256) void gemm_kernel(const float* __restrict__ W,
                                                   const float* __restrict__ bias,
                                                   float* __restrict__ P, // in/out
                                                   int N) {
    __shared__ float Pl[64 * PSTR];      // 33792 B
    __shared__ float Wl[KCHUNK * 128];   // 16384 B  (total 50176 B < 64 KB)
    int tid = threadIdx.x;
    int rbase = blockIdx.x * 64;

    // stage P tile (zero-fill OOB rows)
    #pragma unroll
    for (int i = 0; i < 8; ++i) {
        int idx = tid + i * 256;       // float4 index 0..2047
        int flat = idx * 4;            // 0..8191
        int r = flat >> 7, c = flat & 127;
        int gr = rbase + r;
        float4 p4 = (gr < N) ? *(const float4*)(&P[(size_t)gr * N_FEAT + c])
                             : make_float4(0.f, 0.f, 0.f, 0.f);
        *(float4*)(&Pl[r * PSTR + c]) = p4;
    }

    int r0 = (tid >> 4) * 4;
    int c0 = (tid & 15) * 8;
    float acc[4][8] = {};

    for (int kc = 0; kc < 128; kc += KCHUNK) {
        __syncthreads();
        // stage W chunk: KCHUNK x 128
        #pragma unroll
        for (int i = 0; i < (KCHUNK * 128 / 4) / 256; ++i) {
            int idx = tid + i * 256;   // float4 index
            int flat = idx * 4;
            int kk = flat >> 7, c = flat & 127;
            *(float4*)(&Wl[kk * 128 + c]) =
                *(const float4*)(&W[(kc + kk) * N_FEAT + c]);
        }
        __syncthreads();
        #pragma unroll
        for (int k2 = 0; k2 < KCHUNK; k2 += 4) {
            float4 pr[4];
            #pragma unroll
            for (int i = 0; i < 4; ++i)
                pr[i] = *(const float4*)(&Pl[(r0 + i) * PSTR + kc + k2]);
            #pragma unroll
            for (int j = 0; j < 4; ++j) {
                float4 wa = *(const float4*)(&Wl[(k2 + j) * 128 + c0]);
                float4 wb = *(const float4*)(&Wl[(k2 + j) * 128 + c0 + 4]);
                #pragma unroll
                for (int i = 0; i < 4; ++i) {
                    float pv = ((const float*)&pr[i])[j];
                    acc[i][0] += pv * wa.x; acc[i][1] += pv * wa.y;
                    acc[i][2] += pv * wa.z; acc[i][3] += pv * wa.w;
                    acc[i][4] += pv * wb.x; acc[i][5] += pv * wb.y;
                    acc[i][6] += pv * wb.z; acc[i][7] += pv * wb.w;
                }
            }
        }
    }

    float4 b0 = *(const float4*)(&bias[c0]);
    float4 b1 = *(const float4*)(&bias[c0 + 4]);
    #pragma unroll
    for (int i = 0; i < 4; ++i) {
        int gr = rbase + r0 + i;
        if (gr < N) {
            float4 o0, o1;
            o0.x = fmaxf(acc[i][0] + b0.x, 0.f);
            o0.y = fmaxf(acc[i][1] + b0.y, 0.f);
            o0.z = fmaxf(acc[i][2] + b0.z, 0.f);
            o0.w = fmaxf(acc[i][3] + b0.w, 0.f);
            o1.x = fmaxf(acc[i][4] + b1.x, 0.f);
            o1.y = fmaxf(acc[i][5] + b1.y, 0.f);
            o1.z = fmaxf(acc[i][6] + b1.z, 0.f);
            o1.w = fmaxf(acc[i][7] + b1.w, 0.f);
            *(float4*)(&P[(size_t)gr * N_FEAT + c0])     = o0;
            *(float4*)(&P[(size_t)gr * N_FEAT + c0 + 4]) = o1;
        }
    }
}

// ---------------------------------------------------------------------------
extern "C" void kernel_launch(void* const* d_in, const int* in_sizes, int n_in,
                              void* d_out, int out_size, void* d_ws, size_t ws_size,
                              hipStream_t stream) {
    const float* x      = (const float*)d_in[0];
    const int*   source = (const int*)d_in[1];
    const int*   target = (const int*)d_in[2];
    const float* W      = (const float*)d_in[3];
    const float* bias   = (const float*)d_in[4];
    float*       out    = (float*)d_out;

    const int N = in_sizes[0] / N_FEAT;   // 50000
    const int E = in_sizes[1];            // 800000

    // workspace carve (aligned to 256 B)
    uintptr_t p = (uintptr_t)d_ws;
    auto carve = [&](size_t bytes) {
        p = (p + 255) & ~(uintptr_t)255;
        uintptr_t r = p;
        p += bytes;
        return (void*)r;
    };
    int*   counts  = (int*)carve((size_t)3 * N * sizeof(int)); // deg_out|deg_in|cursor
    int*   deg_out = counts;
    int*   deg_in  = counts + N;
    int*   cursor  = counts + 2 * N;
    float* so      = (float*)carve((size_t)N * sizeof(float));
    float* ri      = (float*)carve((size_t)N * sizeof(float));
    int*   offsets = (int*)carve((size_t)(N + 1) * sizeof(int));
    int*   elist   = (int*)carve((size_t)E * sizeof(int));
    const int nblk = (N + 255) / 256;     // 196
    int*   bsum    = (int*)carve((size_t)nblk * sizeof(int));
    (void)ws_size; (void)n_in; (void)out_size;

    hipMemsetAsync(counts, 0, (size_t)3 * N * sizeof(int), stream);

    hist_kernel<<<(E + 255) / 256, 256, 0, stream>>>(source, target, deg_out, deg_in, E);
    scale_kernel<<<(N + 255) / 256, 256, 0, stream>>>(deg_out, deg_in, so, ri, N);
    block_reduce_kernel<<<nblk, 256, 0, stream>>>(deg_in, bsum, N);
    scan_bsum_kernel<<<1, 256, 0, stream>>>(bsum, nblk);
    scan_final_kernel<<<nblk, 256, 0, stream>>>(deg_in, bsum, offsets, N, E);
    fill_kernel<<<(E + 255) / 256, 256, 0, stream>>>(source, target, offsets, cursor, elist, E);
    agg_kernel<<<(N + 3) / 4, 256, 0, stream>>>(x, elist, offsets, so, ri, out, N);
    gemm_kernel<<<(N + 63) / 64, 256, 0, stream>>>(W, bias, out, N);
}

// Round 3
// 218.635 us; speedup vs baseline: 1.8237x; 1.3306x over previous
//
#include <hip/hip_runtime.h>
#include <hip/hip_bf16.h>

#define N_FEAT 128     // D_FEAT == UNITS == 128
#define EPT 8          // edges per thread in partition passes
#define CHUNK 2048     // 256 threads * EPT
#define BSHIFT 8       // bucket = node >> 8  (bucket range = 256 nodes <= LDS hist)
#define MAXRANGE 256

// ---------------------------------------------------------------------------
// P1: per-block LDS bucket histograms of targets AND sources (no dev atomics).
// countsT layout (transposed for scan): [bucket][block] for targets,
// then [bucket][block] for sources at offset M = NB*NBLK.
// ---------------------------------------------------------------------------
__global__ __launch_bounds__(256) void count_kernel(const int* __restrict__ source,
                                                    const int* __restrict__ target,
                                                    int* __restrict__ countsT,
                                                    int E, int NB, int NBLK) {
    __shared__ int ht[MAXRANGE];
    __shared__ int hs[MAXRANGE];
    int tid = threadIdx.x, b = blockIdx.x;
    for (int k = tid; k < NB; k += 256) { ht[k] = 0; hs[k] = 0; }
    __syncthreads();
    int base = b * CHUNK;
    #pragma unroll
    for (int j = 0; j < EPT; ++j) {
        int e = base + j * 256 + tid;
        if (e < E) {
            atomicAdd(&ht[target[e] >> BSHIFT], 1);
            atomicAdd(&hs[source[e] >> BSHIFT], 1);
        }
    }
    __syncthreads();
    int M = NB * NBLK;
    for (int k = tid; k < NB; k += 256) {
        countsT[k * NBLK + b]     = ht[k];
        countsT[M + k * NBLK + b] = hs[k];
    }
}

// ---------------------------------------------------------------------------
// Hierarchical exclusive scan (generic length M): reduce -> scan bsums -> final
// ---------------------------------------------------------------------------
__global__ void block_reduce_kernel(const int* __restrict__ v,
                                    int* __restrict__ bsum, int M) {
    __shared__ int sb[256];
    int tid = threadIdx.x;
    int i = blockIdx.x * 256 + tid;
    sb[tid] = (i < M) ? v[i] : 0;
    __syncthreads();
    #pragma unroll
    for (int off = 128; off > 0; off >>= 1) {
        if (tid < off) sb[tid] += sb[tid + off];
        __syncthreads();
    }
    if (tid == 0) bsum[blockIdx.x] = sb[0];
}

__global__ void scan_bsum_kernel(int* __restrict__ bsum, int nb) {
    __shared__ int sb[1024];
    int tid = threadIdx.x;
    int v = (tid < nb) ? bsum[tid] : 0;
    sb[tid] = v;
    __syncthreads();
    for (int off = 1; off < 1024; off <<= 1) {
        int t = (tid >= off) ? sb[tid - off] : 0;
        __syncthreads();
        sb[tid] += t;
        __syncthreads();
    }
    if (tid < nb) bsum[tid] = sb[tid] - v;   // exclusive
}

__global__ void scan_final_kernel(const int* __restrict__ v,
                                  const int* __restrict__ bsum,
                                  int* __restrict__ scanned, int M) {
    __shared__ int sb[256];
    int tid = threadIdx.x;
    int i = blockIdx.x * 256 + tid;
    int x = (i < M) ? v[i] : 0;
    sb[tid] = x;
    __syncthreads();
    #pragma unroll
    for (int off = 1; off < 256; off <<= 1) {
        int t = (tid >= off) ? sb[tid - off] : 0;
        __syncthreads();
        sb[tid] += t;
        __syncthreads();
    }
    if (i < M) scanned[i] = bsum[blockIdx.x] + sb[tid] - x;
}

// ---------------------------------------------------------------------------
// P3: scatter edges into bucketed arrays using scanned per-(bucket,block)
// offsets (LDS cursors only). pairsT word = src(16b) | tgt_low8 << 16.
// srcB gets src's low 8 bits (enough for per-bucket deg_out histogram).
// ---------------------------------------------------------------------------
__global__ __launch_bounds__(256) void scatter_kernel(const int* __restrict__ source,
                                                      const int* __restrict__ target,
                                                      const int* __restrict__ scanAll,
                                                      unsigned int* __restrict__ pairsT,
                                                      unsigned char* __restrict__ srcB,
                                                      int E, int NB, int NBLK) {
    __shared__ int ct[MAXRANGE];
    __shared__ int cs[MAXRANGE];
    int tid = threadIdx.x, b = blockIdx.x;
    int M = NB * NBLK;
    for (int k = tid; k < NB; k += 256) {
        ct[k] = scanAll[k * NBLK + b];
        cs[k] = scanAll[M + k * NBLK + b] - E;  // src region rebased to 0
    }
    __syncthreads();
    int base = b * CHUNK;
    #pragma unroll
    for (int j = 0; j < EPT; ++j) {
        int e = base + j * 256 + tid;
        if (e < E) {
            int t = target[e], s = source[e];
            int pt = atomicAdd(&ct[t >> BSHIFT], 1);
            pairsT[pt] = (unsigned)s | ((unsigned)(t & 255) << 16);
            int ps = atomicAdd(&cs[s >> BSHIFT], 1);
            srcB[ps] = (unsigned char)(s & 255);
        }
    }
}

// ---------------------------------------------------------------------------
// P5: per-source-bucket deg_out -> so = rsqrt(max(deg,1)). One block/bucket.
// ---------------------------------------------------------------------------
__global__ __launch_bounds__(256) void so_kernel(const unsigned char* __restrict__ srcB,
                                                 const int* __restrict__ scanAll,
                                                 float* __restrict__ so,
                                                 int N, int NB, int NBLK, int E) {
    __shared__ int hist[MAXRANGE];
    int b = blockIdx.x, tid = threadIdx.x;
    int M = NB * NBLK;
    hist[tid] = 0;
    __syncthreads();
    int start = scanAll[M + b * NBLK] - E;
    int end   = (b + 1 < NB) ? (scanAll[M + (b + 1) * NBLK] - E) : E;
    for (int i = start + tid; i < end; i += 256)
        atomicAdd(&hist[srcB[i]], 1);
    __syncthreads();
    int node = (b << BSHIFT) + tid;
    if (node < N) {
        int d = hist[tid]; if (d < 1) d = 1;
        so[node] = rsqrtf((float)d);
    }
}

// ---------------------------------------------------------------------------
// P4: per-target-bucket CSR: per-node degree (LDS hist) -> ri, local scan ->
// global offsets, then scatter sources into elist. One block per bucket.
// ---------------------------------------------------------------------------
__global__ __launch_bounds__(256) void csr_kernel(const unsigned int* __restrict__ pairsT,
                                                  const int* __restrict__ scanAll,
                                                  int* __restrict__ offsets,
                                                  int* __restrict__ elist,
                                                  float* __restrict__ ri,
                                                  int N, int NB, int NBLK, int E) {
    __shared__ int hist[MAXRANGE];
    __shared__ int sb[MAXRANGE];
    __shared__ int excl[MAXRANGE];
    __shared__ int cur[MAXRANGE];
    int b = blockIdx.x, tid = threadIdx.x;
    hist[tid] = 0; cur[tid] = 0;
    __syncthreads();
    int start = scanAll[b * NBLK];
    int end   = (b + 1 < NB) ? scanAll[(b + 1) * NBLK] : E;
    for (int i = start + tid; i < end; i += 256)
        atomicAdd(&hist[(pairsT[i] >> 16) & 255], 1);
    __syncthreads();
    int deg = hist[tid];
    sb[tid] = deg;
    __syncthreads();
    #pragma unroll
    for (int off = 1; off < 256; off <<= 1) {
        int t = (tid >= off) ? sb[tid - off] : 0;
        __syncthreads();
        sb[tid] += t;
        __syncthreads();
    }
    excl[tid] = sb[tid] - deg;
    __syncthreads();
    int node = (b << BSHIFT) + tid;
    if (node < N) {
        offsets[node] = start + excl[tid];
        int d = deg; if (d < 1) d = 1;
        ri[node] = rsqrtf((float)d);
    }
    if (b == 0 && tid == 0) offsets[N] = E;
    for (int i = start + tid; i < end; i += 256) {
        unsigned w = pairsT[i];
        int tl = (w >> 16) & 255;
        int pos = atomicAdd(&cur[tl], 1);
        elist[start + excl[tl] + pos] = (int)(w & 0xFFFFu);
    }
}

// ---------------------------------------------------------------------------
// K5: pull aggregation — one wave per target node, float2 per lane, x4 unroll.
// ---------------------------------------------------------------------------
__global__ void agg_kernel(const float* __restrict__ x,
                           const int* __restrict__ elist,
                           const int* __restrict__ offsets,
                           const float* __restrict__ so,
                           const float* __restrict__ ri,
                           float* __restrict__ pooled, int N) {
    int wave = (blockIdx.x * blockDim.x + threadIdx.x) >> 6;
    int lane = threadIdx.x & 63;
    if (wave >= N) return;
    int start = offsets[wave];
    int end   = offsets[wave + 1];
    int col = lane * 2;

    float2 a0 = make_float2(0.f, 0.f), a1 = a0, a2 = a0, a3 = a0;
    int i = start;
    for (; i + 4 <= end; i += 4) {
        int e0 = __builtin_amdgcn_readfirstlane(elist[i]);
        int e1 = __builtin_amdgcn_readfirstlane(elist[i + 1]);
        int e2 = __builtin_amdgcn_readfirstlane(elist[i + 2]);
        int e3 = __builtin_amdgcn_readfirstlane(elist[i + 3]);
        float s0 = so[e0], s1 = so[e1], s2 = so[e2], s3 = so[e3];
        float2 v0 = *(const float2*)(&x[(size_t)e0 * N_FEAT + col]);
        float2 v1 = *(const float2*)(&x[(size_t)e1 * N_FEAT + col]);
        float2 v2 = *(const float2*)(&x[(size_t)e2 * N_FEAT + col]);
        float2 v3 = *(const float2*)(&x[(size_t)e3 * N_FEAT + col]);
        a0.x += s0 * v0.x; a0.y += s0 * v0.y;
        a1.x += s1 * v1.x; a1.y += s1 * v1.y;
        a2.x += s2 * v2.x; a2.y += s2 * v2.y;
        a3.x += s3 * v3.x; a3.y += s3 * v3.y;
    }
    for (; i < end; ++i) {
        int e = __builtin_amdgcn_readfirstlane(elist[i]);
        float s = so[e];
        float2 v = *(const float2*)(&x[(size_t)e * N_FEAT + col]);
        a0.x += s * v.x; a0.y += s * v.y;
    }
    float r = ri[wave];
    float2 outv = make_float2((a0.x + a1.x + a2.x + a3.x) * r,
                              (a0.y + a1.y + a2.y + a3.y) * r);
    *(float2*)(&pooled[(size_t)wave * N_FEAT + col]) = outv;
}

// ---------------------------------------------------------------------------
// K6: out = relu(P @ W + b), fp32, in-place on P. 64x128 tile, 4x8/thread.
// fp32 kept: bf16-MFMA rounding tail too close to the 2.56e-2 threshold.
// ---------------------------------------------------------------------------
#define PSTR 132
#define KCHUNK 32

__global__ __launch_bounds__(256) void gemm_kernel(const float* __restrict__ W,
                                                   const float* __restrict__ bias,
                                                   float* __restrict__ P, // in/out
                                                   int N) {
    __shared__ float Pl[64 * PSTR];
    __shared__ float Wl[KCHUNK * 128];
    int tid = threadIdx.x;
    int rbase = blockIdx.x * 64;

    #pragma unroll
    for (int i = 0; i < 8; ++i) {
        int idx = tid + i * 256;
        int flat = idx * 4;
        int r = flat >> 7, c = flat & 127;
        int gr = rbase + r;
        float4 p4 = (gr < N) ? *(const float4*)(&P[(size_t)gr * N_FEAT + c])
                             : make_float4(0.f, 0.f, 0.f, 0.f);
        *(float4*)(&Pl[r * PSTR + c]) = p4;
    }

    int r0 = (tid >> 4) * 4;
    int c0 = (tid & 15) * 8;
    float acc[4][8] = {};

    for (int kc = 0; kc < 128; kc += KCHUNK) {
        __syncthreads();
        #pragma unroll
        for (int i = 0; i < (KCHUNK * 128 / 4) / 256; ++i) {
            int idx = tid + i * 256;
            int flat = idx * 4;
            int kk = flat >> 7, c = flat & 127;
            *(float4*)(&Wl[kk * 128 + c]) =
                *(const float4*)(&W[(kc + kk) * N_FEAT + c]);
        }
        __syncthreads();
        #pragma unroll
        for (int k2 = 0; k2 < KCHUNK; k2 += 4) {
            float4 pr[4];
            #pragma unroll
            for (int i = 0; i < 4; ++i)
                pr[i] = *(const float4*)(&Pl[(r0 + i) * PSTR + kc + k2]);
            #pragma unroll
            for (int j = 0; j < 4; ++j) {
                float4 wa = *(const float4*)(&Wl[(k2 + j) * 128 + c0]);
                float4 wb = *(const float4*)(&Wl[(k2 + j) * 128 + c0 + 4]);
                #pragma unroll
                for (int i = 0; i < 4; ++i) {
                    float pv = ((const float*)&pr[i])[j];
                    acc[i][0] += pv * wa.x; acc[i][1] += pv * wa.y;
                    acc[i][2] += pv * wa.z; acc[i][3] += pv * wa.w;
                    acc[i][4] += pv * wb.x; acc[i][5] += pv * wb.y;
                    acc[i][6] += pv * wb.z; acc[i][7] += pv * wb.w;
                }
            }
        }
    }

    float4 b0 = *(const float4*)(&bias[c0]);
    float4 b1 = *(const float4*)(&bias[c0 + 4]);
    #pragma unroll
    for (int i = 0; i < 4; ++i) {
        int gr = rbase + r0 + i;
        if (gr < N) {
            float4 o0, o1;
            o0.x = fmaxf(acc[i][0] + b0.x, 0.f);
            o0.y = fmaxf(acc[i][1] + b0.y, 0.f);
            o0.z = fmaxf(acc[i][2] + b0.z, 0.f);
            o0.w = fmaxf(acc[i][3] + b0.w, 0.f);
            o1.x = fmaxf(acc[i][4] + b1.x, 0.f);
            o1.y = fmaxf(acc[i][5] + b1.y, 0.f);
            o1.z = fmaxf(acc[i][6] + b1.z, 0.f);
            o1.w = fmaxf(acc[i][7] + b1.w, 0.f);
            *(float4*)(&P[(size_t)gr * N_FEAT + c0])     = o0;
            *(float4*)(&P[(size_t)gr * N_FEAT + c0 + 4]) = o1;
        }
    }
}

// ---------------------------------------------------------------------------
extern "C" void kernel_launch(void* const* d_in, const int* in_sizes, int n_in,
                              void* d_out, int out_size, void* d_ws, size_t ws_size,
                              hipStream_t stream) {
    const float* x      = (const float*)d_in[0];
    const int*   source = (const int*)d_in[1];
    const int*   target = (const int*)d_in[2];
    const float* W      = (const float*)d_in[3];
    const float* bias   = (const float*)d_in[4];
    float*       out    = (float*)d_out;

    const int N = in_sizes[0] / N_FEAT;   // 50000
    const int E = in_sizes[1];            // 800000

    const int NB   = (N + MAXRANGE - 1) >> BSHIFT;  // 196 buckets of <=256 nodes
    const int NBLK = (E + CHUNK - 1) / CHUNK;       // 391 partition blocks
    const int M    = NB * NBLK;
    const int MALL = 2 * M;                          // tgt counts then src counts
    const int nb2  = (MALL + 255) / 256;             // 599 <= 1024

    // workspace carve (aligned to 256 B)
    uintptr_t p = (uintptr_t)d_ws;
    auto carve = [&](size_t bytes) {
        p = (p + 255) & ~(uintptr_t)255;
        uintptr_t r = p;
        p += bytes;
        return (void*)r;
    };
    int*          countsT = (int*)carve((size_t)MALL * sizeof(int));
    int*          scanAll = (int*)carve((size_t)MALL * sizeof(int));
    int*          bsum    = (int*)carve((size_t)nb2 * sizeof(int));
    unsigned int* pairsT  = (unsigned int*)carve((size_t)E * sizeof(unsigned int));
    int*          elist   = (int*)carve((size_t)E * sizeof(int));
    unsigned char* srcB   = (unsigned char*)elist;   // alias: srcB consumed before elist written
    float*        so      = (float*)carve((size_t)N * sizeof(float));
    float*        ri      = (float*)carve((size_t)N * sizeof(float));
    int*          offsets = (int*)carve((size_t)(N + 1) * sizeof(int));
    (void)ws_size; (void)n_in; (void)out_size;

    count_kernel<<<NBLK, 256, 0, stream>>>(source, target, countsT, E, NB, NBLK);
    block_reduce_kernel<<<nb2, 256, 0, stream>>>(countsT, bsum, MALL);
    scan_bsum_kernel<<<1, 1024, 0, stream>>>(bsum, nb2);
    scan_final_kernel<<<nb2, 256, 0, stream>>>(countsT, bsum, scanAll, MALL);
    scatter_kernel<<<NBLK, 256, 0, stream>>>(source, target, scanAll, pairsT, srcB, E, NB, NBLK);
    so_kernel<<<NB, 256, 0, stream>>>(srcB, scanAll, so, N, NB, NBLK, E);   // reads srcB...
    csr_kernel<<<NB, 256, 0, stream>>>(pairsT, scanAll, offsets, elist, ri, N, NB, NBLK, E); // ...then elist overwrites it
    agg_kernel<<<(N + 3) / 4, 256, 0, stream>>>(x, elist, offsets, so, ri, out, N);
    gemm_kernel<<<(N + 63) / 64, 256, 0, stream>>>(W, bias, out, N);
}

// Round 4
// 203.065 us; speedup vs baseline: 1.9635x; 1.0767x over previous
//
#include <hip/hip_runtime.h>
#include <hip/hip_bf16.h>

#define N_FEAT 128     // D_FEAT == UNITS == 128
#define EPT 8          // edges per thread in partition passes
#define CHUNK 2048     // 256 threads * EPT
#define BSHIFT 8       // bucket = node >> 8  (bucket range = 256 nodes <= LDS hist)
#define MAXRANGE 256

// ---------------------------------------------------------------------------
// P1: per-block LDS bucket histograms of targets AND sources (no dev atomics).
// countsT layout (transposed for scan): [bucket][block] targets, then sources.
// ---------------------------------------------------------------------------
__global__ __launch_bounds__(256) void count_kernel(const int* __restrict__ source,
                                                    const int* __restrict__ target,
                                                    int* __restrict__ countsT,
                                                    int E, int NB, int NBLK) {
    __shared__ int ht[MAXRANGE];
    __shared__ int hs[MAXRANGE];
    int tid = threadIdx.x, b = blockIdx.x;
    ht[tid] = 0; hs[tid] = 0;
    __syncthreads();
    int base = b * CHUNK;
    #pragma unroll
    for (int j = 0; j < EPT; ++j) {
        int e = base + j * 256 + tid;
        if (e < E) {
            atomicAdd(&ht[target[e] >> BSHIFT], 1);
            atomicAdd(&hs[source[e] >> BSHIFT], 1);
        }
    }
    __syncthreads();
    int M = NB * NBLK;
    for (int k = tid; k < NB; k += 256) {
        countsT[k * NBLK + b]     = ht[k];
        countsT[M + k * NBLK + b] = hs[k];
    }
}

// ---------------------------------------------------------------------------
// Hierarchical exclusive scan (generic length M)
// ---------------------------------------------------------------------------
__global__ void block_reduce_kernel(const int* __restrict__ v,
                                    int* __restrict__ bsum, int M) {
    __shared__ int sb[256];
    int tid = threadIdx.x;
    int i = blockIdx.x * 256 + tid;
    sb[tid] = (i < M) ? v[i] : 0;
    __syncthreads();
    #pragma unroll
    for (int off = 128; off > 0; off >>= 1) {
        if (tid < off) sb[tid] += sb[tid + off];
        __syncthreads();
    }
    if (tid == 0) bsum[blockIdx.x] = sb[0];
}

__global__ void scan_bsum_kernel(int* __restrict__ bsum, int nb) {
    __shared__ int sb[1024];
    int tid = threadIdx.x;
    int v = (tid < nb) ? bsum[tid] : 0;
    sb[tid] = v;
    __syncthreads();
    for (int off = 1; off < 1024; off <<= 1) {
        int t = (tid >= off) ? sb[tid - off] : 0;
        __syncthreads();
        sb[tid] += t;
        __syncthreads();
    }
    if (tid < nb) bsum[tid] = sb[tid] - v;   // exclusive
}

__global__ void scan_final_kernel(const int* __restrict__ v,
                                  const int* __restrict__ bsum,
                                  int* __restrict__ scanned, int M) {
    __shared__ int sb[256];
    int tid = threadIdx.x;
    int i = blockIdx.x * 256 + tid;
    int x = (i < M) ? v[i] : 0;
    sb[tid] = x;
    __syncthreads();
    #pragma unroll
    for (int off = 1; off < 256; off <<= 1) {
        int t = (tid >= off) ? sb[tid - off] : 0;
        __syncthreads();
        sb[tid] += t;
        __syncthreads();
    }
    if (i < M) scanned[i] = bsum[blockIdx.x] + sb[tid] - x;
}

// ---------------------------------------------------------------------------
// P3: LDS-staged scatter. Edges are binned into LDS first (bucket id recorded
// per item), then copied out as contiguous per-bucket runs (avg ~10 words) so
// global writes are coalesced runs instead of 1.6M isolated 4B transactions.
// pairsT word = src(16b) | tgt_low8 << 16   (valid: N = 50000 < 65536)
// ---------------------------------------------------------------------------
__global__ __launch_bounds__(256) void scatter_kernel(const int* __restrict__ source,
                                                      const int* __restrict__ target,
                                                      const int* __restrict__ scanAll,
                                                      unsigned int* __restrict__ pairsT,
                                                      unsigned char* __restrict__ srcB,
                                                      int E, int NB, int NBLK) {
    __shared__ unsigned int  lds_pairs[CHUNK];   // 8 KB
    __shared__ unsigned char lds_kt[CHUNK];      // 2 KB  (target bucket per item)
    __shared__ unsigned char lds_src[CHUNK];     // 2 KB
    __shared__ unsigned char lds_ks[CHUNK];      // 2 KB  (source bucket per item)
    __shared__ int ct[MAXRANGE], cs[MAXRANGE];   // cursors
    __shared__ int st[MAXRANGE], ss[MAXRANGE];   // frozen exclusive starts
    __shared__ int gt[MAXRANGE], gs[MAXRANGE];   // global base per bucket
    int tid = threadIdx.x, b = blockIdx.x;
    int M = NB * NBLK;
    int base = b * CHUNK;
    int cnt = E - base; if (cnt > CHUNK) cnt = CHUNK;

    ct[tid] = 0; cs[tid] = 0;
    for (int k = tid; k < NB; k += 256) {
        gt[k] = scanAll[k * NBLK + b];
        gs[k] = scanAll[M + k * NBLK + b] - E;   // src region rebased to 0
    }
    __syncthreads();
    // local histograms
    #pragma unroll
    for (int j = 0; j < EPT; ++j) {
        int e = base + j * 256 + tid;
        if (e < E) {
            atomicAdd(&ct[target[e] >> BSHIFT], 1);
            atomicAdd(&cs[source[e] >> BSHIFT], 1);
        }
    }
    __syncthreads();
    // local exclusive scans of both histograms
    int vt = ct[tid], vs = cs[tid];
    st[tid] = vt; ss[tid] = vs;
    __syncthreads();
    #pragma unroll
    for (int off = 1; off < 256; off <<= 1) {
        int t1 = (tid >= off) ? st[tid - off] : 0;
        int t2 = (tid >= off) ? ss[tid - off] : 0;
        __syncthreads();
        st[tid] += t1; ss[tid] += t2;
        __syncthreads();
    }
    int et = st[tid] - vt, es = ss[tid] - vs;
    __syncthreads();
    st[tid] = et; ss[tid] = es;   // frozen starts
    ct[tid] = et; cs[tid] = es;   // cursors
    __syncthreads();
    // bin into LDS
    #pragma unroll
    for (int j = 0; j < EPT; ++j) {
        int e = base + j * 256 + tid;
        if (e < E) {
            int t = target[e], s = source[e];
            int k = t >> BSHIFT;
            int p = atomicAdd(&ct[k], 1);
            lds_pairs[p] = (unsigned)s | ((unsigned)(t & 255) << 16);
            lds_kt[p] = (unsigned char)k;
            int k2 = s >> BSHIFT;
            int p2 = atomicAdd(&cs[k2], 1);
            lds_src[p2] = (unsigned char)(s & 255);
            lds_ks[p2] = (unsigned char)k2;
        }
    }
    __syncthreads();
    // coalesced copy-out (consecutive i in same bucket -> consecutive global)
    for (int i = tid; i < cnt; i += 256) {
        int k = lds_kt[i];
        pairsT[gt[k] + (i - st[k])] = lds_pairs[i];
        int k2 = lds_ks[i];
        srcB[gs[k2] + (i - ss[k2])] = lds_src[i];
    }
}

// ---------------------------------------------------------------------------
// P5: per-source-bucket deg_out -> so = rsqrt(max(deg,1)). One block/bucket.
// ---------------------------------------------------------------------------
__global__ __launch_bounds__(256) void so_kernel(const unsigned char* __restrict__ srcB,
                                                 const int* __restrict__ scanAll,
                                                 float* __restrict__ so,
                                                 int N, int NB, int NBLK, int E) {
    __shared__ int hist[MAXRANGE];
    int b = blockIdx.x, tid = threadIdx.x;
    int M = NB * NBLK;
    hist[tid] = 0;
    __syncthreads();
    int start = scanAll[M + b * NBLK] - E;
    int end   = (b + 1 < NB) ? (scanAll[M + (b + 1) * NBLK] - E) : E;
    for (int i = start + tid; i < end; i += 256)
        atomicAdd(&hist[srcB[i]], 1);
    __syncthreads();
    int node = (b << BSHIFT) + tid;
    if (node < N) {
        int d = hist[tid]; if (d < 1) d = 1;
        so[node] = rsqrtf((float)d);
    }
}

// ---------------------------------------------------------------------------
// P6: xb = bf16(so[row] * x)  — halves the random-gather bytes in agg.
// Accumulation stays fp32; only the gathered operand is rounded (rel ~2^-9).
// ---------------------------------------------------------------------------
__global__ __launch_bounds__(256) void prescale_kernel(const float* __restrict__ x,
                                                       const float* __restrict__ so,
                                                       unsigned short* __restrict__ xb,
                                                       int N) {
    int idx = blockIdx.x * 256 + threadIdx.x;   // one float4 per thread
    int total = N * (N_FEAT / 4);
    if (idx >= total) return;
    int row = idx >> 5;                         // 32 float4 per row
    float s = so[row];
    float4 v = ((const float4*)x)[idx];
    float f[4] = {s * v.x, s * v.y, s * v.z, s * v.w};
    unsigned short o[4];
    #pragma unroll
    for (int j = 0; j < 4; ++j) {               // RTNE f32 -> bf16
        unsigned u = __float_as_uint(f[j]);
        u += 0x7fffu + ((u >> 16) & 1u);
        o[j] = (unsigned short)(u >> 16);
    }
    ((ushort4*)xb)[idx] = make_ushort4(o[0], o[1], o[2], o[3]);
}

// ---------------------------------------------------------------------------
// P4: per-target-bucket CSR: LDS degree hist -> ri, local scan -> offsets,
// scatter sources into elist (scatter stays inside a <=16KB L2-hot region).
// ---------------------------------------------------------------------------
__global__ __launch_bounds__(256) void csr_kernel(const unsigned int* __restrict__ pairsT,
                                                  const int* __restrict__ scanAll,
                                                  int* __restrict__ offsets,
                                                  int* __restrict__ elist,
                                                  float* __restrict__ ri,
                                                  int N, int NB, int NBLK, int E) {
    __shared__ int hist[MAXRANGE];
    __shared__ int sb[MAXRANGE];
    __shared__ int excl[MAXRANGE];
    __shared__ int cur[MAXRANGE];
    int b = blockIdx.x, tid = threadIdx.x;
    hist[tid] = 0; cur[tid] = 0;
    __syncthreads();
    int start = scanAll[b * NBLK];
    int end   = (b + 1 < NB) ? scanAll[(b + 1) * NBLK] : E;
    for (int i = start + tid; i < end; i += 256)
        atomicAdd(&hist[(pairsT[i] >> 16) & 255], 1);
    __syncthreads();
    int deg = hist[tid];
    sb[tid] = deg;
    __syncthreads();
    #pragma unroll
    for (int off = 1; off < 256; off <<= 1) {
        int t = (tid >= off) ? sb[tid - off] : 0;
        __syncthreads();
        sb[tid] += t;
        __syncthreads();
    }
    excl[tid] = sb[tid] - deg;
    __syncthreads();
    int node = (b << BSHIFT) + tid;
    if (node < N) {
        offsets[node] = start + excl[tid];
        int d = deg; if (d < 1) d = 1;
        ri[node] = rsqrtf((float)d);
    }
    if (b == 0 && tid == 0) offsets[N] = E;
    for (int i = start + tid; i < end; i += 256) {
        unsigned w = pairsT[i];
        int tl = (w >> 16) & 255;
        int pos = atomicAdd(&cur[tl], 1);
        elist[start + excl[tl] + pos] = (int)(w & 0xFFFFu);
    }
}

// ---------------------------------------------------------------------------
// K5: pull aggregation over prescaled bf16 rows — one wave per target node,
// 2 features (one packed u32) per lane, x8 unroll for MLP.
// ---------------------------------------------------------------------------
__global__ void agg_kernel(const unsigned short* __restrict__ xb,
                           const int* __restrict__ elist,
                           const int* __restrict__ offsets,
                           const float* __restrict__ ri,
                           float* __restrict__ pooled, int N) {
    int wave = (blockIdx.x * blockDim.x + threadIdx.x) >> 6;
    int lane = threadIdx.x & 63;
    if (wave >= N) return;
    int start = offsets[wave];
    int end   = offsets[wave + 1];
    int col = lane * 2;

    float2 a0 = make_float2(0.f, 0.f), a1 = a0, a2 = a0, a3 = a0;
    int i = start;
    for (; i + 8 <= end; i += 8) {
        int e0 = __builtin_amdgcn_readfirstlane(elist[i]);
        int e1 = __builtin_amdgcn_readfirstlane(elist[i + 1]);
        int e2 = __builtin_amdgcn_readfirstlane(elist[i + 2]);
        int e3 = __builtin_amdgcn_readfirstlane(elist[i + 3]);
        int e4 = __builtin_amdgcn_readfirstlane(elist[i + 4]);
        int e5 = __builtin_amdgcn_readfirstlane(elist[i + 5]);
        int e6 = __builtin_amdgcn_readfirstlane(elist[i + 6]);
        int e7 = __builtin_amdgcn_readfirstlane(elist[i + 7]);
        unsigned u0 = *(const unsigned*)(xb + (size_t)e0 * N_FEAT + col);
        unsigned u1 = *(const unsigned*)(xb + (size_t)e1 * N_FEAT + col);
        unsigned u2 = *(const unsigned*)(xb + (size_t)e2 * N_FEAT + col);
        unsigned u3 = *(const unsigned*)(xb + (size_t)e3 * N_FEAT + col);
        unsigned u4 = *(const unsigned*)(xb + (size_t)e4 * N_FEAT + col);
        unsigned u5 = *(const unsigned*)(xb + (size_t)e5 * N_FEAT + col);
        unsigned u6 = *(const unsigned*)(xb + (size_t)e6 * N_FEAT + col);
        unsigned u7 = *(const unsigned*)(xb + (size_t)e7 * N_FEAT + col);
        a0.x += __uint_as_float(u0 << 16); a0.y += __uint_as_float(u0 & 0xffff0000u);
        a1.x += __uint_as_float(u1 << 16); a1.y += __uint_as_float(u1 & 0xffff0000u);
        a2.x += __uint_as_float(u2 << 16); a2.y += __uint_as_float(u2 & 0xffff0000u);
        a3.x += __uint_as_float(u3 << 16); a3.y += __uint_as_float(u3 & 0xffff0000u);
        a0.x += __uint_as_float(u4 << 16); a0.y += __uint_as_float(u4 & 0xffff0000u);
        a1.x += __uint_as_float(u5 << 16); a1.y += __uint_as_float(u5 & 0xffff0000u);
        a2.x += __uint_as_float(u6 << 16); a2.y += __uint_as_float(u6 & 0xffff0000u);
        a3.x += __uint_as_float(u7 << 16); a3.y += __uint_as_float(u7 & 0xffff0000u);
    }
    for (; i < end; ++i) {
        int e = __builtin_amdgcn_readfirstlane(elist[i]);
        unsigned u = *(const unsigned*)(xb + (size_t)e * N_FEAT + col);
        a0.x += __uint_as_float(u << 16); a0.y += __uint_as_float(u & 0xffff0000u);
    }
    float r = ri[wave];
    float2 outv = make_float2(((a0.x + a1.x) + (a2.x + a3.x)) * r,
                              ((a0.y + a1.y) + (a2.y + a3.y)) * r);
    *(float2*)(&pooled[(size_t)wave * N_FEAT + col]) = outv;
}

// ---------------------------------------------------------------------------
// K6: out = relu(P @ W + b), fp32, in-place on P. 64x128 tile, 4x8/thread.
// fp32 kept: bf16-MFMA rounding would stack on the gather's bf16 error.
// ---------------------------------------------------------------------------
#define PSTR 132
#define KCHUNK 32

__global__ __launch_bounds__(256) void gemm_kernel(const float* __restrict__ W,
                                                   const float* __restrict__ bias,
                                                   float* __restrict__ P, // in/out
                                                   int N) {
    __shared__ float Pl[64 * PSTR];
    __shared__ float Wl[KCHUNK * 128];
    int tid = threadIdx.x;
    int rbase = blockIdx.x * 64;

    #pragma unroll
    for (int i = 0; i < 8; ++i) {
        int idx = tid + i * 256;
        int flat = idx * 4;
        int r = flat >> 7, c = flat & 127;
        int gr = rbase + r;
        float4 p4 = (gr < N) ? *(const float4*)(&P[(size_t)gr * N_FEAT + c])
                             : make_float4(0.f, 0.f, 0.f, 0.f);
        *(float4*)(&Pl[r * PSTR + c]) = p4;
    }

    int r0 = (tid >> 4) * 4;
    int c0 = (tid & 15) * 8;
    float acc[4][8] = {};

    for (int kc = 0; kc < 128; kc += KCHUNK) {
        __syncthreads();
        #pragma unroll
        for (int i = 0; i < (KCHUNK * 128 / 4) / 256; ++i) {
            int idx = tid + i * 256;
            int flat = idx * 4;
            int kk = flat >> 7, c = flat & 127;
            *(float4*)(&Wl[kk * 128 + c]) =
                *(const float4*)(&W[(kc + kk) * N_FEAT + c]);
        }
        __syncthreads();
        #pragma unroll
        for (int k2 = 0; k2 < KCHUNK; k2 += 4) {
            float4 pr[4];
            #pragma unroll
            for (int i = 0; i < 4; ++i)
                pr[i] = *(const float4*)(&Pl[(r0 + i) * PSTR + kc + k2]);
            #pragma unroll
            for (int j = 0; j < 4; ++j) {
                float4 wa = *(const float4*)(&Wl[(k2 + j) * 128 + c0]);
                float4 wb = *(const float4*)(&Wl[(k2 + j) * 128 + c0 + 4]);
                #pragma unroll
                for (int i = 0; i < 4; ++i) {
                    float pv = ((const float*)&pr[i])[j];
                    acc[i][0] += pv * wa.x; acc[i][1] += pv * wa.y;
                    acc[i][2] += pv * wa.z; acc[i][3] += pv * wa.w;
                    acc[i][4] += pv * wb.x; acc[i][5] += pv * wb.y;
                    acc[i][6] += pv * wb.z; acc[i][7] += pv * wb.w;
                }
            }
        }
    }

    float4 b0 = *(const float4*)(&bias[c0]);
    float4 b1 = *(const float4*)(&bias[c0 + 4]);
    #pragma unroll
    for (int i = 0; i < 4; ++i) {
        int gr = rbase + r0 + i;
        if (gr < N) {
            float4 o0, o1;
            o0.x = fmaxf(acc[i][0] + b0.x, 0.f);
            o0.y = fmaxf(acc[i][1] + b0.y, 0.f);
            o0.z = fmaxf(acc[i][2] + b0.z, 0.f);
            o0.w = fmaxf(acc[i][3] + b0.w, 0.f);
            o1.x = fmaxf(acc[i][4] + b1.x, 0.f);
            o1.y = fmaxf(acc[i][5] + b1.y, 0.f);
            o1.z = fmaxf(acc[i][6] + b1.z, 0.f);
            o1.w = fmaxf(acc[i][7] + b1.w, 0.f);
            *(float4*)(&P[(size_t)gr * N_FEAT + c0])     = o0;
            *(float4*)(&P[(size_t)gr * N_FEAT + c0 + 4]) = o1;
        }
    }
}

// ---------------------------------------------------------------------------
extern "C" void kernel_launch(void* const* d_in, const int* in_sizes, int n_in,
                              void* d_out, int out_size, void* d_ws, size_t ws_size,
                              hipStream_t stream) {
    const float* x      = (const float*)d_in[0];
    const int*   source = (const int*)d_in[1];
    const int*   target = (const int*)d_in[2];
    const float* W      = (const float*)d_in[3];
    const float* bias   = (const float*)d_in[4];
    float*       out    = (float*)d_out;

    const int N = in_sizes[0] / N_FEAT;   // 50000
    const int E = in_sizes[1];            // 800000

    const int NB   = (N + MAXRANGE - 1) >> BSHIFT;  // 196
    const int NBLK = (E + CHUNK - 1) / CHUNK;       // 391
    const int M    = NB * NBLK;
    const int MALL = 2 * M;
    const int nb2  = (MALL + 255) / 256;            // <= 1024

    uintptr_t p = (uintptr_t)d_ws;
    auto carve = [&](size_t bytes) {
        p = (p + 255) & ~(uintptr_t)255;
        uintptr_t r = p;
        p += bytes;
        return (void*)r;
    };
    int*           countsT = (int*)carve((size_t)MALL * sizeof(int));
    int*           scanAll = (int*)carve((size_t)MALL * sizeof(int));
    int*           bsum    = (int*)carve((size_t)nb2 * sizeof(int));
    unsigned int*  pairsT  = (unsigned int*)carve((size_t)E * sizeof(unsigned int));
    int*           elist   = (int*)carve((size_t)E * sizeof(int));
    unsigned char* srcB    = (unsigned char*)elist;  // alias: consumed before elist written
    float*         so      = (float*)carve((size_t)N * sizeof(float));
    float*         ri      = (float*)carve((size_t)N * sizeof(float));
    int*           offsets = (int*)carve((size_t)(N + 1) * sizeof(int));
    unsigned short* xb     = (unsigned short*)carve((size_t)N * N_FEAT * sizeof(unsigned short));
    (void)ws_size; (void)n_in; (void)out_size;

    count_kernel<<<NBLK, 256, 0, stream>>>(source, target, countsT, E, NB, NBLK);
    block_reduce_kernel<<<nb2, 256, 0, stream>>>(countsT, bsum, MALL);
    scan_bsum_kernel<<<1, 1024, 0, stream>>>(bsum, nb2);
    scan_final_kernel<<<nb2, 256, 0, stream>>>(countsT, bsum, scanAll, MALL);
    scatter_kernel<<<NBLK, 256, 0, stream>>>(source, target, scanAll, pairsT, srcB, E, NB, NBLK);
    so_kernel<<<NB, 256, 0, stream>>>(srcB, scanAll, so, N, NB, NBLK, E);      // reads srcB...
    prescale_kernel<<<(N * (N_FEAT / 4) + 255) / 256, 256, 0, stream>>>(x, so, xb, N);
    csr_kernel<<<NB, 256, 0, stream>>>(pairsT, scanAll, offsets, elist, ri, N, NB, NBLK, E); // ...then elist overwrites it
    agg_kernel<<<(N + 3) / 4, 256, 0, stream>>>(xb, elist, offsets, ri, out, N);
    gemm_kernel<<<(N + 63) / 64, 256, 0, stream>>>(W, bias, out, N);
}

// Round 5
// 188.526 us; speedup vs baseline: 2.1149x; 1.0771x over previous
//
#include <hip/hip_runtime.h>
#include <hip/hip_bf16.h>

#define N_FEAT 128     // D_FEAT == UNITS == 128
#define EPT 8          // edges per thread in partition passes
#define CHUNK 2048     // 256 threads * EPT
#define BSHIFT 8       // bucket = node >> 8  (bucket range = 256 nodes <= LDS hist)
#define MAXRANGE 256

typedef short bf16x8 __attribute__((ext_vector_type(8)));
typedef float f32x4  __attribute__((ext_vector_type(4)));

__device__ __forceinline__ unsigned short f2bf_rtne(float f) {
    unsigned u = __float_as_uint(f);
    u += 0x7fffu + ((u >> 16) & 1u);
    return (unsigned short)(u >> 16);
}

// ---------------------------------------------------------------------------
// P1: per-block LDS bucket histograms of targets AND sources (no dev atomics).
// countsT layout (transposed for scan): [bucket][block] targets, then sources.
// ---------------------------------------------------------------------------
__global__ __launch_bounds__(256) void count_kernel(const int* __restrict__ source,
                                                    const int* __restrict__ target,
                                                    int* __restrict__ countsT,
                                                    int E, int NB, int NBLK) {
    __shared__ int ht[MAXRANGE];
    __shared__ int hs[MAXRANGE];
    int tid = threadIdx.x, b = blockIdx.x;
    ht[tid] = 0; hs[tid] = 0;
    __syncthreads();
    int base = b * CHUNK;
    #pragma unroll
    for (int j = 0; j < EPT; ++j) {
        int e = base + j * 256 + tid;
        if (e < E) {
            atomicAdd(&ht[target[e] >> BSHIFT], 1);
            atomicAdd(&hs[source[e] >> BSHIFT], 1);
        }
    }
    __syncthreads();
    int M = NB * NBLK;
    for (int k = tid; k < NB; k += 256) {
        countsT[k * NBLK + b]     = ht[k];
        countsT[M + k * NBLK + b] = hs[k];
    }
}

// ---------------------------------------------------------------------------
// Hierarchical exclusive scan (generic length M)
// ---------------------------------------------------------------------------
__global__ void block_reduce_kernel(const int* __restrict__ v,
                                    int* __restrict__ bsum, int M) {
    __shared__ int sb[256];
    int tid = threadIdx.x;
    int i = blockIdx.x * 256 + tid;
    sb[tid] = (i < M) ? v[i] : 0;
    __syncthreads();
    #pragma unroll
    for (int off = 128; off > 0; off >>= 1) {
        if (tid < off) sb[tid] += sb[tid + off];
        __syncthreads();
    }
    if (tid == 0) bsum[blockIdx.x] = sb[0];
}

__global__ void scan_bsum_kernel(int* __restrict__ bsum, int nb) {
    __shared__ int sb[1024];
    int tid = threadIdx.x;
    int v = (tid < nb) ? bsum[tid] : 0;
    sb[tid] = v;
    __syncthreads();
    for (int off = 1; off < 1024; off <<= 1) {
        int t = (tid >= off) ? sb[tid - off] : 0;
        __syncthreads();
        sb[tid] += t;
        __syncthreads();
    }
    if (tid < nb) bsum[tid] = sb[tid] - v;   // exclusive
}

__global__ void scan_final_kernel(const int* __restrict__ v,
                                  const int* __restrict__ bsum,
                                  int* __restrict__ scanned, int M) {
    __shared__ int sb[256];
    int tid = threadIdx.x;
    int i = blockIdx.x * 256 + tid;
    int x = (i < M) ? v[i] : 0;
    sb[tid] = x;
    __syncthreads();
    #pragma unroll
    for (int off = 1; off < 256; off <<= 1) {
        int t = (tid >= off) ? sb[tid - off] : 0;
        __syncthreads();
        sb[tid] += t;
        __syncthreads();
    }
    if (i < M) scanned[i] = bsum[blockIdx.x] + sb[tid] - x;
}

// ---------------------------------------------------------------------------
// P3: LDS-staged scatter -> coalesced per-bucket runs.
// pairsT word = src(16b) | tgt_low8 << 16   (valid: N = 50000 < 65536)
// ---------------------------------------------------------------------------
__global__ __launch_bounds__(256) void scatter_kernel(const int* __restrict__ source,
                                                      const int* __restrict__ target,
                                                      const int* __restrict__ scanAll,
                                                      unsigned int* __restrict__ pairsT,
                                                      unsigned char* __restrict__ srcB,
                                                      int E, int NB, int NBLK) {
    __shared__ unsigned int  lds_pairs[CHUNK];
    __shared__ unsigned char lds_kt[CHUNK];
    __shared__ unsigned char lds_src[CHUNK];
    __shared__ unsigned char lds_ks[CHUNK];
    __shared__ int ct[MAXRANGE], cs[MAXRANGE];
    __shared__ int st[MAXRANGE], ss[MAXRANGE];
    __shared__ int gt[MAXRANGE], gs[MAXRANGE];
    int tid = threadIdx.x, b = blockIdx.x;
    int M = NB * NBLK;
    int base = b * CHUNK;
    int cnt = E - base; if (cnt > CHUNK) cnt = CHUNK;

    ct[tid] = 0; cs[tid] = 0;
    for (int k = tid; k < NB; k += 256) {
        gt[k] = scanAll[k * NBLK + b];
        gs[k] = scanAll[M + k * NBLK + b] - E;
    }
    __syncthreads();
    #pragma unroll
    for (int j = 0; j < EPT; ++j) {
        int e = base + j * 256 + tid;
        if (e < E) {
            atomicAdd(&ct[target[e] >> BSHIFT], 1);
            atomicAdd(&cs[source[e] >> BSHIFT], 1);
        }
    }
    __syncthreads();
    int vt = ct[tid], vs = cs[tid];
    st[tid] = vt; ss[tid] = vs;
    __syncthreads();
    #pragma unroll
    for (int off = 1; off < 256; off <<= 1) {
        int t1 = (tid >= off) ? st[tid - off] : 0;
        int t2 = (tid >= off) ? ss[tid - off] : 0;
        __syncthreads();
        st[tid] += t1; ss[tid] += t2;
        __syncthreads();
    }
    int et = st[tid] - vt, es = ss[tid] - vs;
    __syncthreads();
    st[tid] = et; ss[tid] = es;
    ct[tid] = et; cs[tid] = es;
    __syncthreads();
    #pragma unroll
    for (int j = 0; j < EPT; ++j) {
        int e = base + j * 256 + tid;
        if (e < E) {
            int t = target[e], s = source[e];
            int k = t >> BSHIFT;
            int p = atomicAdd(&ct[k], 1);
            lds_pairs[p] = (unsigned)s | ((unsigned)(t & 255) << 16);
            lds_kt[p] = (unsigned char)k;
            int k2 = s >> BSHIFT;
            int p2 = atomicAdd(&cs[k2], 1);
            lds_src[p2] = (unsigned char)(s & 255);
            lds_ks[p2] = (unsigned char)k2;
        }
    }
    __syncthreads();
    for (int i = tid; i < cnt; i += 256) {
        int k = lds_kt[i];
        pairsT[gt[k] + (i - st[k])] = lds_pairs[i];
        int k2 = lds_ks[i];
        srcB[gs[k2] + (i - ss[k2])] = lds_src[i];
    }
}

// ---------------------------------------------------------------------------
// P5: per-source-bucket deg_out -> so = rsqrt(max(deg,1)). One block/bucket.
// ---------------------------------------------------------------------------
__global__ __launch_bounds__(256) void so_kernel(const unsigned char* __restrict__ srcB,
                                                 const int* __restrict__ scanAll,
                                                 float* __restrict__ so,
                                                 int N, int NB, int NBLK, int E) {
    __shared__ int hist[MAXRANGE];
    int b = blockIdx.x, tid = threadIdx.x;
    int M = NB * NBLK;
    hist[tid] = 0;
    __syncthreads();
    int start = scanAll[M + b * NBLK] - E;
    int end   = (b + 1 < NB) ? (scanAll[M + (b + 1) * NBLK] - E) : E;
    for (int i = start + tid; i < end; i += 256)
        atomicAdd(&hist[srcB[i]], 1);
    __syncthreads();
    int node = (b << BSHIFT) + tid;
    if (node < N) {
        int d = hist[tid]; if (d < 1) d = 1;
        so[node] = rsqrtf((float)d);
    }
}

// ---------------------------------------------------------------------------
// P6: xb = bf16(so[row] * x)  — halves the random-gather bytes in agg.
// ---------------------------------------------------------------------------
__global__ __launch_bounds__(256) void prescale_kernel(const float* __restrict__ x,
                                                       const float* __restrict__ so,
                                                       unsigned short* __restrict__ xb,
                                                       int N) {
    int idx = blockIdx.x * 256 + threadIdx.x;   // one float4 per thread
    int total = N * (N_FEAT / 4);
    if (idx >= total) return;
    int row = idx >> 5;                         // 32 float4 per row
    float s = so[row];
    float4 v = ((const float4*)x)[idx];
    unsigned short o[4] = {f2bf_rtne(s * v.x), f2bf_rtne(s * v.y),
                           f2bf_rtne(s * v.z), f2bf_rtne(s * v.w)};
    ((ushort4*)xb)[idx] = make_ushort4(o[0], o[1], o[2], o[3]);
}

// ---------------------------------------------------------------------------
// P7: pack W into MFMA B-fragment order, split hi/lo bf16.
// Fragment (ct, ks, lane) holds B[k][n]: n = ct*16 + (lane&15),
// k = ks*32 + (lane>>4)*8 + j, j=0..7, stored contiguously at
// ((ct*4+ks)*64 + lane)*8. 2048 threads total.
// ---------------------------------------------------------------------------
__global__ __launch_bounds__(256) void wpack_kernel(const float* __restrict__ W,
                                                    unsigned short* __restrict__ Whi,
                                                    unsigned short* __restrict__ Wlo) {
    int idx = blockIdx.x * 256 + threadIdx.x;   // 0..2047
    int lane = idx & 63;
    int ks = (idx >> 6) & 3;
    int ct = idx >> 8;
    int n  = ct * 16 + (lane & 15);
    int k0 = ks * 32 + (lane >> 4) * 8;
    unsigned short h[8], l[8];
    #pragma unroll
    for (int j = 0; j < 8; ++j) {
        float w = W[(k0 + j) * N_FEAT + n];
        unsigned short hh = f2bf_rtne(w);
        float fh = __uint_as_float((unsigned)hh << 16);
        h[j] = hh;
        l[j] = f2bf_rtne(w - fh);
    }
    size_t off = (size_t)idx * 8;
    *(ushort4*)(Whi + off)     = make_ushort4(h[0], h[1], h[2], h[3]);
    *(ushort4*)(Whi + off + 4) = make_ushort4(h[4], h[5], h[6], h[7]);
    *(ushort4*)(Wlo + off)     = make_ushort4(l[0], l[1], l[2], l[3]);
    *(ushort4*)(Wlo + off + 4) = make_ushort4(l[4], l[5], l[6], l[7]);
}

// ---------------------------------------------------------------------------
// P4: per-target-bucket CSR build. One block per bucket.
// ---------------------------------------------------------------------------
__global__ __launch_bounds__(256) void csr_kernel(const unsigned int* __restrict__ pairsT,
                                                  const int* __restrict__ scanAll,
                                                  int* __restrict__ offsets,
                                                  int* __restrict__ elist,
                                                  float* __restrict__ ri,
                                                  int N, int NB, int NBLK, int E) {
    __shared__ int hist[MAXRANGE];
    __shared__ int sb[MAXRANGE];
    __shared__ int excl[MAXRANGE];
    __shared__ int cur[MAXRANGE];
    int b = blockIdx.x, tid = threadIdx.x;
    hist[tid] = 0; cur[tid] = 0;
    __syncthreads();
    int start = scanAll[b * NBLK];
    int end   = (b + 1 < NB) ? scanAll[(b + 1) * NBLK] : E;
    for (int i = start + tid; i < end; i += 256)
        atomicAdd(&hist[(pairsT[i] >> 16) & 255], 1);
    __syncthreads();
    int deg = hist[tid];
    sb[tid] = deg;
    __syncthreads();
    #pragma unroll
    for (int off = 1; off < 256; off <<= 1) {
        int t = (tid >= off) ? sb[tid - off] : 0;
        __syncthreads();
        sb[tid] += t;
        __syncthreads();
    }
    excl[tid] = sb[tid] - deg;
    __syncthreads();
    int node = (b << BSHIFT) + tid;
    if (node < N) {
        offsets[node] = start + excl[tid];
        int d = deg; if (d < 1) d = 1;
        ri[node] = rsqrtf((float)d);
    }
    if (b == 0 && tid == 0) offsets[N] = E;
    for (int i = start + tid; i < end; i += 256) {
        unsigned w = pairsT[i];
        int tl = (w >> 16) & 255;
        int pos = atomicAdd(&cur[tl], 1);
        elist[start + excl[tl] + pos] = (int)(w & 0xFFFFu);
    }
}

// ---------------------------------------------------------------------------
// K5: pull aggregation over prescaled bf16 rows — one wave per target node,
// 2 features (one packed u32) per lane, x8 unroll for MLP. fp32 accumulate.
// ---------------------------------------------------------------------------
__global__ void agg_kernel(const unsigned short* __restrict__ xb,
                           const int* __restrict__ elist,
                           const int* __restrict__ offsets,
                           const float* __restrict__ ri,
                           float* __restrict__ pooled, int N) {
    int wave = (blockIdx.x * blockDim.x + threadIdx.x) >> 6;
    int lane = threadIdx.x & 63;
    if (wave >= N) return;
    int start = offsets[wave];
    int end   = offsets[wave + 1];
    int col = lane * 2;

    float2 a0 = make_float2(0.f, 0.f), a1 = a0, a2 = a0, a3 = a0;
    int i = start;
    for (; i + 8 <= end; i += 8) {
        int e0 = __builtin_amdgcn_readfirstlane(elist[i]);
        int e1 = __builtin_amdgcn_readfirstlane(elist[i + 1]);
        int e2 = __builtin_amdgcn_readfirstlane(elist[i + 2]);
        int e3 = __builtin_amdgcn_readfirstlane(elist[i + 3]);
        int e4 = __builtin_amdgcn_readfirstlane(elist[i + 4]);
        int e5 = __builtin_amdgcn_readfirstlane(elist[i + 5]);
        int e6 = __builtin_amdgcn_readfirstlane(elist[i + 6]);
        int e7 = __builtin_amdgcn_readfirstlane(elist[i + 7]);
        unsigned u0 = *(const unsigned*)(xb + (size_t)e0 * N_FEAT + col);
        unsigned u1 = *(const unsigned*)(xb + (size_t)e1 * N_FEAT + col);
        unsigned u2 = *(const unsigned*)(xb + (size_t)e2 * N_FEAT + col);
        unsigned u3 = *(const unsigned*)(xb + (size_t)e3 * N_FEAT + col);
        unsigned u4 = *(const unsigned*)(xb + (size_t)e4 * N_FEAT + col);
        unsigned u5 = *(const unsigned*)(xb + (size_t)e5 * N_FEAT + col);
        unsigned u6 = *(const unsigned*)(xb + (size_t)e6 * N_FEAT + col);
        unsigned u7 = *(const unsigned*)(xb + (size_t)e7 * N_FEAT + col);
        a0.x += __uint_as_float(u0 << 16); a0.y += __uint_as_float(u0 & 0xffff0000u);
        a1.x += __uint_as_float(u1 << 16); a1.y += __uint_as_float(u1 & 0xffff0000u);
        a2.x += __uint_as_float(u2 << 16); a2.y += __uint_as_float(u2 & 0xffff0000u);
        a3.x += __uint_as_float(u3 << 16); a3.y += __uint_as_float(u3 & 0xffff0000u);
        a0.x += __uint_as_float(u4 << 16); a0.y += __uint_as_float(u4 & 0xffff0000u);
        a1.x += __uint_as_float(u5 << 16); a1.y += __uint_as_float(u5 & 0xffff0000u);
        a2.x += __uint_as_float(u6 << 16); a2.y += __uint_as_float(u6 & 0xffff0000u);
        a3.x += __uint_as_float(u7 << 16); a3.y += __uint_as_float(u7 & 0xffff0000u);
    }
    for (; i < end; ++i) {
        int e = __builtin_amdgcn_readfirstlane(elist[i]);
        unsigned u = *(const unsigned*)(xb + (size_t)e * N_FEAT + col);
        a0.x += __uint_as_float(u << 16); a0.y += __uint_as_float(u & 0xffff0000u);
    }
    float r = ri[wave];
    float2 outv = make_float2(((a0.x + a1.x) + (a2.x + a3.x)) * r,
                              ((a0.y + a1.y) + (a2.y + a3.y)) * r);
    *(float2*)(&pooled[(size_t)wave * N_FEAT + col]) = outv;
}

// ---------------------------------------------------------------------------
// K6: out = relu(P @ W + b) via split-bf16 MFMA (bf16x3), in-place on P.
// No LDS (R4: 3.2M bank conflicts, 50KB LDS capped occupancy at 3 blocks/CU).
// Each wave: 16 rows x 128 cols. A split hi/lo in-register from fp32 P;
// W pre-packed in B-fragment order (hi/lo). Error of dropped lo*lo ~1e-4.
// mfma_f32_16x16x32_bf16: A[m=lane&15][k=quad*8+j], B[k=quad*8+j][n=lane&15],
// C/D[row=quad*4+reg][col=lane&15]  (verified layouts, learn_hip m89/m91).
// ---------------------------------------------------------------------------
__global__ __launch_bounds__(256) void gemm_mfma_kernel(const unsigned short* __restrict__ Whi,
                                                        const unsigned short* __restrict__ Wlo,
                                                        const float* __restrict__ bias,
                                                        float* __restrict__ P,  // in/out
                                                        int N) {
    int wave = threadIdx.x >> 6;
    int lane = threadIdx.x & 63;
    int quad = lane >> 4;
    int rowbase = blockIdx.x * 64 + wave * 16;
    int m = rowbase + (lane & 15);
    int mload = (m < N) ? m : 0;            // clamp; garbage unused for OOB rows

    // Load this wave's 16 P rows and split to bf16 hi/lo fragments (4 K-steps)
    bf16x8 Ahi[4], Alo[4];
    const float* prow = P + (size_t)mload * N_FEAT + quad * 8;
    #pragma unroll
    for (int ks = 0; ks < 4; ++ks) {
        float4 v0 = *(const float4*)(prow + ks * 32);
        float4 v1 = *(const float4*)(prow + ks * 32 + 4);
        float f[8] = {v0.x, v0.y, v0.z, v0.w, v1.x, v1.y, v1.z, v1.w};
        bf16x8 h, l;
        #pragma unroll
        for (int j = 0; j < 8; ++j) {
            unsigned short hh = f2bf_rtne(f[j]);
            h[j] = (short)hh;
            l[j] = (short)f2bf_rtne(f[j] - __uint_as_float((unsigned)hh << 16));
        }
        Ahi[ks] = h; Alo[ks] = l;
    }

    const bf16x8* BH = (const bf16x8*)Whi;
    const bf16x8* BL = (const bf16x8*)Wlo;

    #pragma unroll
    for (int ct = 0; ct < 8; ++ct) {
        f32x4 acc = {0.f, 0.f, 0.f, 0.f};
        #pragma unroll
        for (int ks = 0; ks < 4; ++ks) {
            bf16x8 bh = BH[(ct * 4 + ks) * 64 + lane];
            bf16x8 bl = BL[(ct * 4 + ks) * 64 + lane];
            acc = __builtin_amdgcn_mfma_f32_16x16x32_bf16(Ahi[ks], bh, acc, 0, 0, 0);
            acc = __builtin_amdgcn_mfma_f32_16x16x32_bf16(Alo[ks], bh, acc, 0, 0, 0);
            acc = __builtin_amdgcn_mfma_f32_16x16x32_bf16(Ahi[ks], bl, acc, 0, 0, 0);
        }
        int colc = ct * 16 + (lane & 15);
        float bv = bias[colc];
        #pragma unroll
        for (int reg = 0; reg < 4; ++reg) {
            int r = rowbase + quad * 4 + reg;
            if (r < N)
                P[(size_t)r * N_FEAT + colc] = fmaxf(acc[reg] + bv, 0.f);
        }
    }
}

// ---------------------------------------------------------------------------
extern "C" void kernel_launch(void* const* d_in, const int* in_sizes, int n_in,
                              void* d_out, int out_size, void* d_ws, size_t ws_size,
                              hipStream_t stream) {
    const float* x      = (const float*)d_in[0];
    const int*   source = (const int*)d_in[1];
    const int*   target = (const int*)d_in[2];
    const float* W      = (const float*)d_in[3];
    const float* bias   = (const float*)d_in[4];
    float*       out    = (float*)d_out;

    const int N = in_sizes[0] / N_FEAT;   // 50000
    const int E = in_sizes[1];            // 800000

    const int NB   = (N + MAXRANGE - 1) >> BSHIFT;  // 196
    const int NBLK = (E + CHUNK - 1) / CHUNK;       // 391
    const int M    = NB * NBLK;
    const int MALL = 2 * M;
    const int nb2  = (MALL + 255) / 256;            // <= 1024

    uintptr_t p = (uintptr_t)d_ws;
    auto carve = [&](size_t bytes) {
        p = (p + 255) & ~(uintptr_t)255;
        uintptr_t r = p;
        p += bytes;
        return (void*)r;
    };
    int*            countsT = (int*)carve((size_t)MALL * sizeof(int));
    int*            scanAll = (int*)carve((size_t)MALL * sizeof(int));
    int*            bsum    = (int*)carve((size_t)nb2 * sizeof(int));
    unsigned int*   pairsT  = (unsigned int*)carve((size_t)E * sizeof(unsigned int));
    int*            elist   = (int*)carve((size_t)E * sizeof(int));
    unsigned char*  srcB    = (unsigned char*)elist;  // alias: consumed before elist written
    float*          so      = (float*)carve((size_t)N * sizeof(float));
    float*          ri      = (float*)carve((size_t)N * sizeof(float));
    int*            offsets = (int*)carve((size_t)(N + 1) * sizeof(int));
    unsigned short* xb      = (unsigned short*)carve((size_t)N * N_FEAT * sizeof(unsigned short));
    unsigned short* Whi     = (unsigned short*)carve((size_t)N_FEAT * N_FEAT * sizeof(unsigned short));
    unsigned short* Wlo     = (unsigned short*)carve((size_t)N_FEAT * N_FEAT * sizeof(unsigned short));
    (void)ws_size; (void)n_in; (void)out_size;

    count_kernel<<<NBLK, 256, 0, stream>>>(source, target, countsT, E, NB, NBLK);
    block_reduce_kernel<<<nb2, 256, 0, stream>>>(countsT, bsum, MALL);
    scan_bsum_kernel<<<1, 1024, 0, stream>>>(bsum, nb2);
    scan_final_kernel<<<nb2, 256, 0, stream>>>(countsT, bsum, scanAll, MALL);
    scatter_kernel<<<NBLK, 256, 0, stream>>>(source, target, scanAll, pairsT, srcB, E, NB, NBLK);
    so_kernel<<<NB, 256, 0, stream>>>(srcB, scanAll, so, N, NB, NBLK, E);      // reads srcB...
    prescale_kernel<<<(N * (N_FEAT / 4) + 255) / 256, 256, 0, stream>>>(x, so, xb, N);
    wpack_kernel<<<8, 256, 0, stream>>>(W, Whi, Wlo);
    csr_kernel<<<NB, 256, 0, stream>>>(pairsT, scanAll, offsets, elist, ri, N, NB, NBLK, E); // ...then elist overwrites it
    agg_kernel<<<(N + 3) / 4, 256, 0, stream>>>(xb, elist, offsets, ri, out, N);
    gemm_mfma_kernel<<<(N + 63) / 64, 256, 0, stream>>>(Whi, Wlo, bias, out, N);
}